// Round 16
// baseline (73.012 us; speedup 1.0000x reference)
//
#include <hip/hip_runtime.h>

#define WIN    7
#define IMH    640
#define IMW    640
#define OHH    634            // IMH - WIN + 1
#define OWW    634
#define NB     64
#define NBANDS 32
#define BROWS  20             // 31*20 + 14 = 634 output rows
#define NCT    5              // column tiles of 128 output cols
#define NTASK  (NB * NBANDS * NCT)   // 10240 wave-tasks
#define WPB    8              // waves per block (512 threads)
#define TPW    2              // tasks per wave (sequential, adjacent)
#define NBLK   (NTASK / (WPB * TPW))  // 640 blocks
#define DEPTH  2              // prefetch depth (r10/r13 sweet spot)
#define NSLOT  (DEPTH + 1)

// Native 2-wide float vector -> v_pk_add_f32 / v_pk_fma_f32 (r13-proven).
typedef float v2f __attribute__((ext_vector_type(2)));

struct __align__(16) f4v { v2f lo, hi; };   // loads as global_load_dwordx4

// r13's band loop, unchanged: DEPTH-2 register prefetch (mod-3 buffers),
// fully unrolled (all indices static, rule #20), packed column-pair math,
// SSIM epilogue with one combined rcp.
template<int NROWS>
__device__ double band_loop(const float* __restrict__ Xp,
                            const float* __restrict__ Yp,
                            float C1s, float C2s, bool active)
{
    const v2f C1v  = {C1s, C1s};
    const v2f C2v  = {C2s, C2s};
    const v2f covh = {(49.0f / 48.0f) * 0.5f, (49.0f / 48.0f) * 0.5f};
    const v2f zero = {0.f, 0.f};

    v2f rS[WIN], rD[WIN], rSS[WIN], rDD[WIN];
    #pragma unroll
    for (int u = 0; u < WIN; ++u) { rS[u]=zero; rD[u]=zero; rSS[u]=zero; rDD[u]=zero; }
    v2f VS = zero, VD = zero, VSS = zero, VDD = zero;

    f4v bufx[NSLOT][2], bufy[NSLOT][2];
    double acc  = 0.0;
    float  esum = 0.f;

#define LOADROW(P, R) do {                                                    \
    const size_t o_ = (size_t)(R) * IMW;                                      \
    bufx[P][0] = *(const f4v*)(Xp + o_);                                      \
    bufx[P][1] = *(const f4v*)(Xp + o_ + 4);                                  \
    bufy[P][0] = *(const f4v*)(Yp + o_);                                      \
    bufy[P][1] = *(const f4v*)(Yp + o_ + 4);                                  \
} while (0)

    LOADROW(0, 0); LOADROW(1, 1);       // prologue: rows 0,1 in flight

    #pragma unroll
    for (int u = 0; u < NROWS; ++u) {
        if (u + DEPTH < NROWS) LOADROW((u + DEPTH) % NSLOT, u + DEPTH);

        {
            const f4v xa = bufx[u % NSLOT][0], xb = bufx[u % NSLOT][1];
            const f4v ya = bufy[u % NSLOT][0], yb = bufy[u % NSLOT][1];

            const v2f s01 = xa.lo + ya.lo, s23 = xa.hi + ya.hi;
            const v2f s45 = xb.lo + yb.lo, s67 = xb.hi + yb.hi;
            const v2f d01 = xa.lo - ya.lo, d23 = xa.hi - ya.hi;
            const v2f d45 = xb.lo - yb.lo, d67 = xb.hi - yb.hi;

            const v2f ts  = (s01 + s23) + (s45 + s67);
            const v2f td  = (d01 + d23) + (d45 + d67);
            const v2f tqs = (s01*s01 + s23*s23) + (s45*s45 + s67*s67);
            const v2f tqd = (d01*d01 + d23*d23) + (d45*d45 + d67*d67);

            const float EOs  = ts.x + ts.y,   EOd  = td.x + td.y;
            const float EOss = tqs.x + tqs.y, EOdd = tqd.x + tqd.y;
            v2f hS, hD, hSS, hDD;
            hS.x  = EOs  - s67.y;           hS.y  = EOs  - s01.x;
            hD.x  = EOd  - d67.y;           hD.y  = EOd  - d01.x;
            hSS.x = EOss - s67.y * s67.y;   hSS.y = EOss - s01.x * s01.x;
            hDD.x = EOdd - d67.y * d67.y;   hDD.y = EOdd - d01.x * d01.x;

            const int sl = u % WIN;         // compile-time (fully unrolled)
            VS  += hS  - rS[sl];   VD  += hD  - rD[sl];
            VSS += hSS - rSS[sl];  VDD += hDD - rDD[sl];
            rS[sl] = hS; rD[sl] = hD; rSS[sl] = hSS; rDD[sl] = hDD;

            if (u >= WIN - 1 && active) {
                const v2f a  = VS * VS, b = VD * VD;
                const v2f pd = a - b,  ps = a + b;
                const v2f A1 = 0.5f * pd + C1v;
                const v2f B1 = 0.5f * ps + C1v;
                const v2f t1 = VSS - VDD,  t2 = VSS + VDD;
                const v2f w1 = 49.0f * t1 - pd;
                const v2f w2 = 49.0f * t2 - ps;
                const v2f A2 = covh * w1 + C2v;
                const v2f B2 = covh * w2 + C2v;
                const v2f N  = A1 * A2, D = B1 * B2;
                const float Dp  = D.x * D.y;
                const float num = fmaf(N.y, D.x, N.x * D.y);
                esum = fmaf(num, __builtin_amdgcn_rcpf(Dp), esum);
            }
        }

        if (u % WIN == WIN - 1 || u == NROWS - 1) {   // compile-time
            acc += (double)esum;
            esum = 0.f;
        }
    }
#undef LOADROW
    return acc;
}

// Runs ONE task (image b, band, col-tile); returns its partial sum.
__device__ double run_task(const float* __restrict__ X,
                           const float* __restrict__ Y,
                           const float* __restrict__ dr,
                           int task, int lane)
{
    const int tile = task % NCT;
    const int band = (task / NCT) % NBANDS;
    const int b    = task / (NCT * NBANDS);

    const int r0 = band * BROWS;

    const int  ocol   = tile * 128 + 2 * lane;
    const int  cbase  = min(ocol, IMW - 8);
    const bool active = (ocol <= OWW - 2);

    const size_t ioff = (size_t)b * IMH * IMW + (size_t)r0 * IMW + cbase;
    const float* Xp = X + ioff;
    const float* Yp = Y + ioff;

    const float drv = dr[b];
    const float C1s = 2401.0f * (0.01f * drv) * (0.01f * drv);
    const float C2s = 2401.0f * (0.03f * drv) * (0.03f * drv);

    if (band < NBANDS - 1)
        return band_loop<BROWS + WIN - 1>(Xp, Yp, C1s, C2s, active);   // 26 rows
    else
        return band_loop<IMH - (NBANDS - 1) * BROWS>(Xp, Yp, C1s, C2s, active); // 20
}

// 8 independent waves per block, TPW adjacent tasks per wave (sequential).
// Fewer, longer-lived blocks: 640 vs 2560 — tests the CP block-dispatch-rate
// occupancy theory (r16). Only inter-wave interaction is the final reduce.
__global__ __launch_bounds__(512, 2) void ssim_stream(
    const float* __restrict__ X, const float* __restrict__ Y,
    const float* __restrict__ dr, double* __restrict__ partial)
{
    __shared__ double sred[WPB];

    const int tid  = threadIdx.x;
    const int lane = tid & 63;
    const int wv   = tid >> 6;

    const int t0 = (blockIdx.x * WPB + wv) * TPW;   // adjacent tasks: halo L2-warm

    double acc = run_task(X, Y, dr, t0,     lane)
               + run_task(X, Y, dr, t0 + 1, lane);

    for (int off = 32; off > 0; off >>= 1)
        acc += __shfl_down(acc, off, 64);
    if (lane == 0) sred[wv] = acc;
    __syncthreads();
    if (tid == 0) {
        double t = 0.0;
        #pragma unroll
        for (int k = 0; k < WPB; ++k) t += sred[k];
        partial[blockIdx.x] = t;
    }
}

__global__ __launch_bounds__(512) void ssim_reduce(
    const double* __restrict__ partial, int n, float* __restrict__ out)
{
    double acc = 0.0;
    for (int i = threadIdx.x; i < n; i += 512) acc += partial[i];
    for (int off = 32; off > 0; off >>= 1)
        acc += __shfl_down(acc, off, 64);
    __shared__ double sred[8];
    if ((threadIdx.x & 63) == 0) sred[threadIdx.x >> 6] = acc;
    __syncthreads();
    if (threadIdx.x == 0) {
        double t = 0.0;
        #pragma unroll
        for (int k = 0; k < 8; ++k) t += sred[k];
        double denom = (double)NB * (double)OHH * (double)OWW;
        out[0] = (float)(t / denom);
    }
}

extern "C" void kernel_launch(void* const* d_in, const int* in_sizes, int n_in,
                              void* d_out, int out_size, void* d_ws, size_t ws_size,
                              hipStream_t stream) {
    const float* X  = (const float*)d_in[0];
    const float* Y  = (const float*)d_in[1];
    const float* dr = (const float*)d_in[2];
    // d_in[3] is w = ones/49; constant-folded in-kernel.
    double* partial = (double*)d_ws;   // 640 * 8 B = 5 KB scratch

    ssim_stream<<<NBLK, 512, 0, stream>>>(X, Y, dr, partial);
    ssim_reduce<<<1, 512, 0, stream>>>(partial, NBLK, (float*)d_out);
}

// Round 17
// 47.728 us; speedup vs baseline: 1.5298x; 1.5298x over previous
//
#include <hip/hip_runtime.h>

#define WIN    7
#define IMH    640
#define IMW    640
#define OHH    634            // IMH - WIN + 1
#define OWW    634
#define NB     64
#define NBANDS 32
#define BROWS  20             // 31*20 + 14 = 634 output rows
#define NCT    5              // column tiles of 128 output cols
#define WPB    4              // waves per block = 4 vertically-adjacent bands
#define NBLK   (NB * NCT * (NBANDS / WPB))   // 2560 blocks
#define DEPTH  2              // prefetch depth (r10/r13 sweet spot)
#define NSLOT  (DEPTH + 1)

// Native 2-wide float vector -> v_pk_add_f32 / v_pk_fma_f32 (r13-proven).
typedef float v2f __attribute__((ext_vector_type(2)));

struct __align__(16) f4v { v2f lo, hi; };   // loads as global_load_dwordx4

// r13's band loop, byte-identical: DEPTH-2 register prefetch (mod-3 buffers),
// fully unrolled (all indices static, rule #20), packed column-pair math,
// SSIM epilogue with one combined rcp.
template<int NROWS>
__device__ double band_loop(const float* __restrict__ Xp,
                            const float* __restrict__ Yp,
                            float C1s, float C2s, bool active)
{
    const v2f C1v  = {C1s, C1s};
    const v2f C2v  = {C2s, C2s};
    const v2f covh = {(49.0f / 48.0f) * 0.5f, (49.0f / 48.0f) * 0.5f};
    const v2f zero = {0.f, 0.f};

    v2f rS[WIN], rD[WIN], rSS[WIN], rDD[WIN];
    #pragma unroll
    for (int u = 0; u < WIN; ++u) { rS[u]=zero; rD[u]=zero; rSS[u]=zero; rDD[u]=zero; }
    v2f VS = zero, VD = zero, VSS = zero, VDD = zero;

    f4v bufx[NSLOT][2], bufy[NSLOT][2];
    double acc  = 0.0;
    float  esum = 0.f;

#define LOADROW(P, R) do {                                                    \
    const size_t o_ = (size_t)(R) * IMW;                                      \
    bufx[P][0] = *(const f4v*)(Xp + o_);                                      \
    bufx[P][1] = *(const f4v*)(Xp + o_ + 4);                                  \
    bufy[P][0] = *(const f4v*)(Yp + o_);                                      \
    bufy[P][1] = *(const f4v*)(Yp + o_ + 4);                                  \
} while (0)

    LOADROW(0, 0); LOADROW(1, 1);       // prologue: rows 0,1 in flight

    #pragma unroll
    for (int u = 0; u < NROWS; ++u) {
        if (u + DEPTH < NROWS) LOADROW((u + DEPTH) % NSLOT, u + DEPTH);

        {
            const f4v xa = bufx[u % NSLOT][0], xb = bufx[u % NSLOT][1];
            const f4v ya = bufy[u % NSLOT][0], yb = bufy[u % NSLOT][1];

            const v2f s01 = xa.lo + ya.lo, s23 = xa.hi + ya.hi;
            const v2f s45 = xb.lo + yb.lo, s67 = xb.hi + yb.hi;
            const v2f d01 = xa.lo - ya.lo, d23 = xa.hi - ya.hi;
            const v2f d45 = xb.lo - yb.lo, d67 = xb.hi - yb.hi;

            const v2f ts  = (s01 + s23) + (s45 + s67);
            const v2f td  = (d01 + d23) + (d45 + d67);
            const v2f tqs = (s01*s01 + s23*s23) + (s45*s45 + s67*s67);
            const v2f tqd = (d01*d01 + d23*d23) + (d45*d45 + d67*d67);

            const float EOs  = ts.x + ts.y,   EOd  = td.x + td.y;
            const float EOss = tqs.x + tqs.y, EOdd = tqd.x + tqd.y;
            v2f hS, hD, hSS, hDD;
            hS.x  = EOs  - s67.y;           hS.y  = EOs  - s01.x;
            hD.x  = EOd  - d67.y;           hD.y  = EOd  - d01.x;
            hSS.x = EOss - s67.y * s67.y;   hSS.y = EOss - s01.x * s01.x;
            hDD.x = EOdd - d67.y * d67.y;   hDD.y = EOdd - d01.x * d01.x;

            const int sl = u % WIN;         // compile-time (fully unrolled)
            VS  += hS  - rS[sl];   VD  += hD  - rD[sl];
            VSS += hSS - rSS[sl];  VDD += hDD - rDD[sl];
            rS[sl] = hS; rD[sl] = hD; rSS[sl] = hSS; rDD[sl] = hDD;

            if (u >= WIN - 1 && active) {
                const v2f a  = VS * VS, b = VD * VD;
                const v2f pd = a - b,  ps = a + b;
                const v2f A1 = 0.5f * pd + C1v;
                const v2f B1 = 0.5f * ps + C1v;
                const v2f t1 = VSS - VDD,  t2 = VSS + VDD;
                const v2f w1 = 49.0f * t1 - pd;
                const v2f w2 = 49.0f * t2 - ps;
                const v2f A2 = covh * w1 + C2v;
                const v2f B2 = covh * w2 + C2v;
                const v2f N  = A1 * A2, D = B1 * B2;
                const float Dp  = D.x * D.y;
                const float num = fmaf(N.y, D.x, N.x * D.y);
                esum = fmaf(num, __builtin_amdgcn_rcpf(Dp), esum);
            }
        }

        if (u % WIN == WIN - 1 || u == NROWS - 1) {   // compile-time
            acc += (double)esum;
            esum = 0.f;
        }
    }
#undef LOADROW
    return acc;
}

// Block = one (image, tile, band-group): its 4 waves process 4 vertically-
// adjacent bands of the SAME 128-col tile, so each band's 6-row halo (23% of
// all loads) is re-read from the same CU's L1/L2 instead of a remote XCD's
// L3/HBM (r17 theory). Blocks are XCD-clustered: blockIdx n runs task-block
// (n%8)*320 + n/8, so XCD k (HW round-robin) gets a contiguous range = whole
// images (8 per XCD) incl. all band-groups of each column strip.
__global__ __launch_bounds__(256, 2) void ssim_stream(
    const float* __restrict__ X, const float* __restrict__ Y,
    const float* __restrict__ dr, double* __restrict__ partial)
{
    __shared__ double sred[WPB];

    const int tid  = threadIdx.x;
    const int lane = tid & 63;
    const int wv   = tid >> 6;

    const int bid = blockIdx.x;                      // 0..2559
    const int tb  = ((bid & 7) * (NBLK / 8)) + (bid >> 3);  // XCD-clustered
    const int g   = tb & 7;                          // band-group 0..7
    const int bt  = tb >> 3;                         // b*NCT + tile
    const int b   = bt / NCT;
    const int tile = bt - b * NCT;
    const int band = g * WPB + wv;                   // 0..31

    const int r0 = band * BROWS;

    const int  ocol   = tile * 128 + 2 * lane;
    const int  cbase  = min(ocol, IMW - 8);
    const bool active = (ocol <= OWW - 2);

    const size_t ioff = (size_t)b * IMH * IMW + (size_t)r0 * IMW + cbase;
    const float* Xp = X + ioff;
    const float* Yp = Y + ioff;

    const float drv = dr[b];
    const float C1s = 2401.0f * (0.01f * drv) * (0.01f * drv);
    const float C2s = 2401.0f * (0.03f * drv) * (0.03f * drv);

    double acc;
    if (band < NBANDS - 1) {
        acc = band_loop<BROWS + WIN - 1>(Xp, Yp, C1s, C2s, active);   // 26 rows
    } else {
        acc = band_loop<IMH - (NBANDS - 1) * BROWS>(Xp, Yp, C1s, C2s, active); // 20
    }

    for (int off = 32; off > 0; off >>= 1)
        acc += __shfl_down(acc, off, 64);
    if (lane == 0) sred[wv] = acc;
    __syncthreads();
    if (tid == 0) {
        double t = 0.0;
        #pragma unroll
        for (int k = 0; k < WPB; ++k) t += sred[k];
        partial[bid] = t;
    }
}

__global__ __launch_bounds__(512) void ssim_reduce(
    const double* __restrict__ partial, int n2, float* __restrict__ out)
{
    const double2* p2 = (const double2*)partial;
    double acc = 0.0;
    for (int i = threadIdx.x; i < n2; i += 512) {
        double2 v = p2[i];
        acc += v.x + v.y;
    }
    for (int off = 32; off > 0; off >>= 1)
        acc += __shfl_down(acc, off, 64);
    __shared__ double sred[8];
    if ((threadIdx.x & 63) == 0) sred[threadIdx.x >> 6] = acc;
    __syncthreads();
    if (threadIdx.x == 0) {
        double t = 0.0;
        #pragma unroll
        for (int k = 0; k < 8; ++k) t += sred[k];
        double denom = (double)NB * (double)OHH * (double)OWW;
        out[0] = (float)(t / denom);
    }
}

extern "C" void kernel_launch(void* const* d_in, const int* in_sizes, int n_in,
                              void* d_out, int out_size, void* d_ws, size_t ws_size,
                              hipStream_t stream) {
    const float* X  = (const float*)d_in[0];
    const float* Y  = (const float*)d_in[1];
    const float* dr = (const float*)d_in[2];
    // d_in[3] is w = ones/49; constant-folded in-kernel.
    double* partial = (double*)d_ws;   // 2560 * 8 B = 20 KB scratch

    ssim_stream<<<NBLK, 256, 0, stream>>>(X, Y, dr, partial);
    ssim_reduce<<<1, 512, 0, stream>>>(partial, NBLK / 2, (float*)d_out);
}